// Round 4
// baseline (227.290 us; speedup 1.0000x reference)
//
#include <hip/hip_runtime.h>
#include <cstdint>
#include <cstddef>

typedef _Float16 f16;
typedef _Float16 f16x4 __attribute__((ext_vector_type(4)));
typedef _Float16 f16x8 __attribute__((ext_vector_type(8)));
typedef float    f32x4 __attribute__((ext_vector_type(4)));

#define NB 64
#define NN 262144   // 512*512

__device__ __forceinline__ void gload_lds16(const void* g, void* l) {
    __builtin_amdgcn_global_load_lds(
        (const __attribute__((address_space(1))) void*)g,
        (__attribute__((address_space(3))) void*)l, 16, 0, 0);
}

// Stage A: part[b][ch][n] = sum of 32 rows of adj[b][:, n]
__global__ void k_colsum_part(const float* __restrict__ adj, float* __restrict__ part) {
    int b = blockIdx.y, ch = blockIdx.x;          // ch 0..15
    const float* ab = adj + (size_t)b * NN + (size_t)ch * 32 * 512;
    int c = threadIdx.x;                          // 0..255
    float s0 = 0.f, s1 = 0.f;
    #pragma unroll 8
    for (int i = 0; i < 32; ++i) {
        s0 += ab[i * 512 + c];
        s1 += ab[i * 512 + c + 256];
    }
    float* p = part + ((size_t)b * 16 + ch) * 512;
    p[c] = s0; p[c + 256] = s1;
}

// Merged prep: [0,8192) cvtX ; [8192,8384) transW ; [8384,8512) colsum_fin
__global__ void k_prep(const float* __restrict__ X0, f16* __restrict__ X_h,
                       const float* __restrict__ W1, const float* __restrict__ W2,
                       const float* __restrict__ W3, f16* __restrict__ Wt,
                       const float* __restrict__ part, float* __restrict__ r) {
    const int bid = blockIdx.x;
    if (bid < 8192) {
        size_t i = ((size_t)bid * 256 + threadIdx.x) * 8;
        float4 v0 = *(const float4*)(X0 + i);
        float4 v1 = *(const float4*)(X0 + i + 4);
        f16x8 o;
        o[0] = (f16)v0.x; o[1] = (f16)v0.y; o[2] = (f16)v0.z; o[3] = (f16)v0.w;
        o[4] = (f16)v1.x; o[5] = (f16)v1.y; o[6] = (f16)v1.z; o[7] = (f16)v1.w;
        *(f16x8*)(X_h + i) = o;
    } else if (bid < 8384) {
        __shared__ float t[64][65];
        int tt = bid - 8192;
        int z = tt >> 6, rem = tt & 63;
        const float* W = z == 0 ? W1 : (z == 1 ? W2 : W3);
        f16* out = Wt + (size_t)z * NN;
        int k0 = (rem >> 3) * 64, d0 = (rem & 7) * 64;
        int c = threadIdx.x & 63, r4 = threadIdx.x >> 6;
        #pragma unroll
        for (int s = 0; s < 16; ++s) {
            int rr = r4 + s * 4;
            t[rr][c] = W[(size_t)(k0 + rr) * 512 + d0 + c];
        }
        __syncthreads();
        int kq = (threadIdx.x & 15) * 4;
        int db = threadIdx.x >> 4;
        #pragma unroll
        for (int s = 0; s < 4; ++s) {
            int dd = db + s * 16;
            f16x4 o;
            #pragma unroll
            for (int q = 0; q < 4; ++q)
                o[q] = (f16)(64.f * t[kq + q][dd]);
            *(f16x4*)&out[(size_t)(d0 + dd) * 512 + k0 + kq] = o;
        }
    } else {
        int idx = (bid - 8384) * 256 + threadIdx.x;   // 0..32767
        int b = idx >> 9, n = idx & 511;
        const float* p = part + (size_t)b * 16 * 512 + n;
        float s = 0.f;
        #pragma unroll
        for (int ch = 0; ch < 16; ++ch) s += p[ch * 512];
        r[idx] = (s > 0.f) ? rsqrtf(s) : 0.f;
    }
}

// A_h[b][i][j] = f16( 16 * r[b][i] * adj[b][j][i] * r[b][j] )   (tiled transpose)
__global__ void k_makeA(const float* __restrict__ adj, const float* __restrict__ r,
                        f16* __restrict__ A_h) {
    __shared__ float t[64][65];
    int b = blockIdx.z;
    int i0 = blockIdx.y * 64, j0 = blockIdx.x * 64;
    const float* ab = adj + (size_t)b * NN;
    int c = threadIdx.x & 63, r4 = threadIdx.x >> 6;
    #pragma unroll
    for (int s = 0; s < 16; ++s) {
        int rr = r4 + s * 4;
        t[rr][c] = ab[(size_t)(j0 + rr) * 512 + i0 + c];   // t[j][i]
    }
    __syncthreads();
    const float* rb = r + (size_t)b * 512;
    f16* Ab = A_h + (size_t)b * NN;
    int jq = (threadIdx.x & 15) * 4;
    int ib = threadIdx.x >> 4;
    #pragma unroll
    for (int s = 0; s < 4; ++s) {
        int ii = ib + s * 16;
        float ri = 16.f * rb[i0 + ii];
        f16x4 o;
        #pragma unroll
        for (int q = 0; q < 4; ++q)
            o[q] = (f16)(ri * t[jq + q][ii] * rb[j0 + jq + q]);
        *(f16x4*)&Ab[(size_t)(i0 + ii) * 512 + j0 + jq] = o;
    }
}

// C[m][n] = sum_k P[m][k] * Qt[n][k];  out Ct[n][m] = act(C*iscale + bias[m]) * oscale
// 128x128 tile, BK=64, 4 waves (2Mx2N), double-buffered LDS (64 KiB -> 2 WG/CU),
// counted-vmcnt pipeline, both-sides XOR slot swizzle.
template<bool BIAS, bool RELU, bool OUTF32>
__global__ __launch_bounds__(256, 2)
void gemm_tn_ct(const f16* __restrict__ P, size_t pstr,
                const f16* __restrict__ Qt, size_t qstr,
                void* __restrict__ Cout, size_t cstr,
                const float* __restrict__ bias, float iscale, float oscale) {
    __shared__ __align__(16) f16 Plds[2][8192];   // 2 x 128x64 f16 = 32 KiB
    __shared__ __align__(16) f16 Qlds[2][8192];   // 32 KiB

    const int tid  = threadIdx.x;
    const int lane = tid & 63;
    const int wid  = tid >> 6;          // 0..3
    const int wm   = wid >> 1;          // M half (64 rows)
    const int wn   = wid & 1;           // N half (64 cols)

    // XCD-contiguous swizzle: 1024 WGs, 8 XCDs x 128 WGs = 8 batches/XCD
    const int wg  = blockIdx.x;
    const int swz = (wg & 7) * 128 + (wg >> 3);
    const int b   = swz >> 4;
    const int tt  = swz & 15;
    const int m0  = (tt >> 2) * 128;
    const int n0  = (tt & 3) * 128;

    const f16* Pb = P + (size_t)b * pstr;
    const f16* Qb = Qt + (size_t)b * qstr;

    // staging geometry: 256 threads; row covers 8 slots of 16B; 32 rows/round
    const int srow = tid >> 3;                      // 0..31
    const int sswz = (tid & 7) ^ (srow & 7);        // swizzled source slot

    // fragment geometry
    const int fr  = lane & 15;
    const int fs  = lane >> 4;          // base slot 0..3 (krep adds 4)
    const int fx  = fr & 7;             // read-side XOR (row&7 == fr&7)

    auto stage = [&](const f16* __restrict__ Gb, int row0, f16* lds, int k0) {
        #pragma unroll
        for (int r = 0; r < 4; ++r) {
            const f16* src = Gb + (size_t)(row0 + r * 32 + srow) * 512 + k0 + sswz * 8;
            gload_lds16(src, lds + r * 2048 + tid * 8);
        }
    };

    f32x4 acc[4][4] = {};

    // prologue: stage tile 0 into buffer 0 (8 vmem/wave outstanding)
    stage(Pb, m0, &Plds[0][0], 0);
    stage(Qb, n0, &Qlds[0][0], 0);

    for (int t = 0; t < 8; ++t) {
        const int nb = t & 1;
        if (t < 7) {
            stage(Pb, m0, &Plds[nb ^ 1][0], (t + 1) * 64);
            stage(Qb, n0, &Qlds[nb ^ 1][0], (t + 1) * 64);
            asm volatile("s_waitcnt vmcnt(8)" ::: "memory");   // tile t landed; t+1 in flight
        } else {
            asm volatile("s_waitcnt vmcnt(0)" ::: "memory");
        }
        __builtin_amdgcn_s_barrier();

        const f16* Pl = &Plds[nb][0];
        const f16* Ql = &Qlds[nb][0];
        #pragma unroll
        for (int krep = 0; krep < 2; ++krep) {
            const int sp = ((fs + krep * 4) ^ fx) * 8;
            f16x8 af[4], bf[4];
            #pragma unroll
            for (int mi = 0; mi < 4; ++mi)
                af[mi] = *(const f16x8*)&Pl[(wm * 64 + mi * 16 + fr) * 64 + sp];
            #pragma unroll
            for (int ni = 0; ni < 4; ++ni)
                bf[ni] = *(const f16x8*)&Ql[(wn * 64 + ni * 16 + fr) * 64 + sp];
            __builtin_amdgcn_s_setprio(1);
            #pragma unroll
            for (int mi = 0; mi < 4; ++mi)
                #pragma unroll
                for (int ni = 0; ni < 4; ++ni)
                    acc[mi][ni] = __builtin_amdgcn_mfma_f32_16x16x32_f16(
                        af[mi], bf[ni], acc[mi][ni], 0, 0, 0);
            __builtin_amdgcn_s_setprio(0);
        }
        // all LDS reads of this tile serviced before anyone re-stages this buffer
        asm volatile("s_waitcnt lgkmcnt(0)" ::: "memory");
        __builtin_amdgcn_sched_barrier(0);
        __builtin_amdgcn_s_barrier();
    }

    // epilogue: Ct[n][m], frag: n = lane&15 (col), m = (lane>>4)*4 + reg (row)
    const int cmb = (lane >> 4) * 4;
    #pragma unroll
    for (int mi = 0; mi < 4; ++mi) {
        #pragma unroll
        for (int ni = 0; ni < 4; ++ni) {
            const int n = n0 + wn * 64 + ni * 16 + fr;
            const int m = m0 + wm * 64 + mi * 16 + cmb;
            float v[4];
            #pragma unroll
            for (int q = 0; q < 4; ++q) {
                float x = acc[mi][ni][q] * iscale;
                if (BIAS) x += bias[m + q];
                if (RELU) x = fmaxf(x, 0.f);
                v[q] = x * oscale;
            }
            if (OUTF32) {
                float* Cb = (float*)Cout + (size_t)b * cstr;
                f32x4 o; o[0] = v[0]; o[1] = v[1]; o[2] = v[2]; o[3] = v[3];
                *(f32x4*)&Cb[(size_t)n * 512 + m] = o;
            } else {
                f16* Cb = (f16*)Cout + (size_t)b * cstr;
                f16x4 o; o[0] = (f16)v[0]; o[1] = (f16)v[1]; o[2] = (f16)v[2]; o[3] = (f16)v[3];
                *(f16x4*)&Cb[(size_t)n * 512 + m] = o;
            }
        }
    }
}

extern "C" void kernel_launch(void* const* d_in, const int* in_sizes, int n_in,
                              void* d_out, int out_size, void* d_ws, size_t ws_size,
                              hipStream_t stream) {
    const float* X0  = (const float*)d_in[0];
    const float* adj = (const float*)d_in[1];
    const float* W1  = (const float*)d_in[2];
    const float* b1  = (const float*)d_in[3];
    const float* W2  = (const float*)d_in[4];
    const float* b2  = (const float*)d_in[5];
    const float* W3  = (const float*)d_in[6];
    const float* b3  = (const float*)d_in[7];

    uint8_t* ws = (uint8_t*)d_ws;
    float* rbuf = (float*)ws;                              // 128 KiB
    f16* Wt1 = (f16*)(ws + 131072);                        // 3 x 512 KiB
    f16* Wt2 = Wt1 + NN;
    f16* Wt3 = Wt2 + NN;
    f16* A_h = (f16*)(ws + 131072 + (size_t)3 * NN * 2);   // 32 MiB
    f16* X_h = A_h + (size_t)NB * NN;                      // 32 MiB
    f16* S_t = X_h + (size_t)NB * NN;                      // 32 MiB
    float* part = (float*)S_t;   // 2 MiB, aliased: S_t first written later by GEMM1

    k_colsum_part<<<dim3(16, 64), dim3(256), 0, stream>>>(adj, part);
    k_prep <<<dim3(8512),      dim3(256), 0, stream>>>(X0, X_h, W1, W2, W3, Wt1, part, rbuf);
    k_makeA<<<dim3(8, 8, NB),  dim3(256), 0, stream>>>(adj, rbuf, A_h);

    dim3 gg(1024), gb(256);
    // scales: X stored x1 (layer1) / x256 (layer3 input); W stored x64; A stored x16.
    gemm_tn_ct<false, false, false><<<gg, gb, 0, stream>>>(X_h, (size_t)NN, Wt1, (size_t)0,  S_t, (size_t)NN, nullptr, 1.f, 1.f / 64.f);
    gemm_tn_ct<true,  true,  false><<<gg, gb, 0, stream>>>(S_t, (size_t)NN, A_h, (size_t)NN, X_h, (size_t)NN, b1, 1.f / 16.f, 1.f);
    gemm_tn_ct<false, false, false><<<gg, gb, 0, stream>>>(X_h, (size_t)NN, Wt2, (size_t)0,  S_t, (size_t)NN, nullptr, 1.f, 4.f);
    gemm_tn_ct<true,  true,  false><<<gg, gb, 0, stream>>>(S_t, (size_t)NN, A_h, (size_t)NN, X_h, (size_t)NN, b2, 1.f / 4096.f, 256.f);
    gemm_tn_ct<false, false, false><<<gg, gb, 0, stream>>>(X_h, (size_t)NN, Wt3, (size_t)0,  S_t, (size_t)NN, nullptr, 1.f, 1.f / 64.f);
    gemm_tn_ct<true,  false, true ><<<gg, gb, 0, stream>>>(S_t, (size_t)NN, A_h, (size_t)NN, d_out, (size_t)NN, b3, 1.f / 4096.f, 1.f);
}

// Round 5
// 223.643 us; speedup vs baseline: 1.0163x; 1.0163x over previous
//
#include <hip/hip_runtime.h>
#include <cstdint>
#include <cstddef>

typedef _Float16 f16;
typedef _Float16 f16x4 __attribute__((ext_vector_type(4)));
typedef _Float16 f16x8 __attribute__((ext_vector_type(8)));
typedef float    f32x4 __attribute__((ext_vector_type(4)));

#define NB 64
#define NN 262144   // 512*512

__device__ __forceinline__ void gload_lds16(const void* g, void* l) {
    __builtin_amdgcn_global_load_lds(
        (const __attribute__((address_space(1))) void*)g,
        (__attribute__((address_space(3))) void*)l, 16, 0, 0);
}

// merged: [0,1024) colsum partials ; [1024,1216) transW
__global__ void k_aux1(const float* __restrict__ adj, float* __restrict__ part,
                       const float* __restrict__ W1, const float* __restrict__ W2,
                       const float* __restrict__ W3, f16* __restrict__ Wt) {
    __shared__ float t[64][65];
    const int bid = blockIdx.x;
    if (bid < 1024) {
        int b = bid >> 4, ch = bid & 15;
        const float* ab = adj + (size_t)b * NN + (size_t)ch * 32 * 512;
        int c = threadIdx.x;
        float s0 = 0.f, s1 = 0.f;
        #pragma unroll 8
        for (int i = 0; i < 32; ++i) {
            s0 += ab[i * 512 + c];
            s1 += ab[i * 512 + c + 256];
        }
        float* p = part + ((size_t)b * 16 + ch) * 512;
        p[c] = s0; p[c + 256] = s1;
    } else {
        int tt = bid - 1024;
        int z = tt >> 6, rem = tt & 63;
        const float* W = z == 0 ? W1 : (z == 1 ? W2 : W3);
        f16* out = Wt + (size_t)z * NN;
        int k0 = (rem >> 3) * 64, d0 = (rem & 7) * 64;
        int c = threadIdx.x & 63, r4 = threadIdx.x >> 6;
        #pragma unroll
        for (int s = 0; s < 16; ++s) {
            int rr = r4 + s * 4;
            t[rr][c] = W[(size_t)(k0 + rr) * 512 + d0 + c];
        }
        __syncthreads();
        int kq = (threadIdx.x & 15) * 4;
        int db = threadIdx.x >> 4;
        #pragma unroll
        for (int s = 0; s < 4; ++s) {
            int dd = db + s * 16;
            f16x4 o;
            #pragma unroll
            for (int q = 0; q < 4; ++q)
                o[q] = (f16)(64.f * t[kq + q][dd]);
            *(f16x4*)&out[(size_t)(d0 + dd) * 512 + k0 + kq] = o;
        }
    }
}

// r[b][n] = rsqrt(sum_ch part) with 0 -> 0
__global__ void k_fin(const float* __restrict__ part, float* __restrict__ r) {
    int idx = blockIdx.x * 256 + threadIdx.x;
    int b = idx >> 9, n = idx & 511;
    const float* p = part + (size_t)b * 16 * 512 + n;
    float s = 0.f;
    #pragma unroll
    for (int ch = 0; ch < 16; ++ch) s += p[ch * 512];
    r[idx] = (s > 0.f) ? rsqrtf(s) : 0.f;
}

// A_h[b][i][j] = f16( 16 * r[b][i] * adj[b][j][i] * r[b][j] )
__global__ void k_makeA(const float* __restrict__ adj, const float* __restrict__ r,
                        f16* __restrict__ A_h) {
    __shared__ float t[64][65];
    int b = blockIdx.z;
    int i0 = blockIdx.y * 64, j0 = blockIdx.x * 64;
    const float* ab = adj + (size_t)b * NN;
    int c = threadIdx.x & 63, r4 = threadIdx.x >> 6;
    #pragma unroll
    for (int s = 0; s < 16; ++s) {
        int rr = r4 + s * 4;
        t[rr][c] = ab[(size_t)(j0 + rr) * 512 + i0 + c];
    }
    __syncthreads();
    const float* rb = r + (size_t)b * 512;
    f16* Ab = A_h + (size_t)b * NN;
    int jq = (threadIdx.x & 15) * 4;
    int ib = threadIdx.x >> 4;
    #pragma unroll
    for (int s = 0; s < 4; ++s) {
        int ii = ib + s * 16;
        float ri = 16.f * rb[i0 + ii];
        f16x4 o;
        #pragma unroll
        for (int q = 0; q < 4; ++q)
            o[q] = (f16)(ri * t[jq + q][ii] * rb[j0 + jq + q]);
        *(f16x4*)&Ab[(size_t)(i0 + ii) * 512 + j0 + jq] = o;
    }
}

// ---------------- G1: S1^T = (X0 @ W1)^T, X0 read as f32 with reg-staged cvt.
// 128x128 tile, BK=64, 4 waves, single barrier per K-tile.
__global__ __launch_bounds__(256, 2)
void gemm_cvt(const float* __restrict__ X0, const f16* __restrict__ Wt,
              f16* __restrict__ S_t, float oscale) {
    __shared__ __align__(16) f16 Plds[2][8192];
    __shared__ __align__(16) f16 Qlds[2][8192];

    const int tid  = threadIdx.x;
    const int lane = tid & 63;
    const int wid  = tid >> 6;
    const int wm   = wid >> 1, wn = wid & 1;

    const int wg  = blockIdx.x;
    const int swz = (wg & 7) * 128 + (wg >> 3);
    const int b   = swz >> 4;
    const int tt  = swz & 15;
    const int m0  = (tt >> 2) * 128;
    const int n0  = (tt & 3) * 128;

    const float* Pb = X0 + (size_t)b * NN;
    const f16*   Qb = Wt;

    const int srow = tid >> 3;                   // 0..31
    const int sswz = (tid & 7) ^ (srow & 7);
    const int cch  = (tid & 7) ^ ((tid >> 3) & 7);  // cvt source chunk (indep of r)

    const int fr  = lane & 15;
    const int fs  = lane >> 4;
    const int fx  = fr & 7;

    auto stageQ = [&](f16* lds, int k0) {
        #pragma unroll
        for (int r = 0; r < 4; ++r) {
            const f16* src = Qb + (size_t)(n0 + r * 32 + srow) * 512 + k0 + sswz * 8;
            gload_lds16(src, lds + r * 2048 + tid * 8);
        }
    };
    float4 pv[4][2];
    auto loadP = [&](int k0) {
        #pragma unroll
        for (int r = 0; r < 4; ++r) {
            const float* src = Pb + (size_t)(m0 + r * 32 + (tid >> 3)) * 512 + k0 + cch * 8;
            pv[r][0] = *(const float4*)src;
            pv[r][1] = *(const float4*)(src + 4);
        }
    };
    auto writeP = [&](f16* lds) {
        #pragma unroll
        for (int r = 0; r < 4; ++r) {
            f16x8 o;
            o[0] = (f16)pv[r][0].x; o[1] = (f16)pv[r][0].y;
            o[2] = (f16)pv[r][0].z; o[3] = (f16)pv[r][0].w;
            o[4] = (f16)pv[r][1].x; o[5] = (f16)pv[r][1].y;
            o[6] = (f16)pv[r][1].z; o[7] = (f16)pv[r][1].w;
            *(f16x8*)(lds + r * 2048 + tid * 8) = o;
        }
    };

    f32x4 acc[4][4] = {};

    // prologue: tile 0
    loadP(0);
    stageQ(&Qlds[0][0], 0);
    asm volatile("s_waitcnt vmcnt(4)" ::: "memory");
    writeP(&Plds[0][0]);
    asm volatile("s_waitcnt vmcnt(0) lgkmcnt(0)" ::: "memory");
    __builtin_amdgcn_sched_barrier(0);
    __builtin_amdgcn_s_barrier();

    for (int t = 0; t < 8; ++t) {
        const int nb = t & 1;
        if (t < 7) {
            loadP((t + 1) * 64);
            stageQ(&Qlds[nb ^ 1][0], (t + 1) * 64);
        }
        const f16* Pl = &Plds[nb][0];
        const f16* Ql = &Qlds[nb][0];
        #pragma unroll
        for (int krep = 0; krep < 2; ++krep) {
            const int sp = ((fs + krep * 4) ^ fx) * 8;
            f16x8 af[4], bf[4];
            #pragma unroll
            for (int mi = 0; mi < 4; ++mi)
                af[mi] = *(const f16x8*)&Pl[(wm * 64 + mi * 16 + fr) * 64 + sp];
            #pragma unroll
            for (int ni = 0; ni < 4; ++ni)
                bf[ni] = *(const f16x8*)&Ql[(wn * 64 + ni * 16 + fr) * 64 + sp];
            __builtin_amdgcn_s_setprio(1);
            #pragma unroll
            for (int mi = 0; mi < 4; ++mi)
                #pragma unroll
                for (int ni = 0; ni < 4; ++ni)
                    acc[mi][ni] = __builtin_amdgcn_mfma_f32_16x16x32_f16(
                        af[mi], bf[ni], acc[mi][ni], 0, 0, 0);
            __builtin_amdgcn_s_setprio(0);
        }
        if (t < 7) {
            asm volatile("s_waitcnt vmcnt(4)" ::: "memory");   // P f32 regs landed
            writeP(&Plds[nb ^ 1][0]);
        }
        asm volatile("s_waitcnt vmcnt(0) lgkmcnt(0)" ::: "memory");
        __builtin_amdgcn_sched_barrier(0);
        __builtin_amdgcn_s_barrier();
    }

    const int cmb = (lane >> 4) * 4;
    #pragma unroll
    for (int mi = 0; mi < 4; ++mi) {
        #pragma unroll
        for (int ni = 0; ni < 4; ++ni) {
            const int n = n0 + wn * 64 + ni * 16 + fr;
            const int m = m0 + wm * 64 + mi * 16 + cmb;
            f16x4 o;
            #pragma unroll
            for (int q = 0; q < 4; ++q) o[q] = (f16)(acc[mi][ni][q] * oscale);
            *(f16x4*)&S_t[(size_t)b * NN + (size_t)n * 512 + m] = o;
        }
    }
}

// ---------------- G2..G6: 256x256 tile, BK=64, 8 waves, single barrier per K-tile.
template<bool BIAS, bool RELU, bool OUTF32>
__global__ __launch_bounds__(512, 1)
void gemm_tn_ct(const f16* __restrict__ P, size_t pstr,
                const f16* __restrict__ Qt, size_t qstr,
                void* __restrict__ Cout, size_t cstr,
                const float* __restrict__ bias, float iscale, float oscale) {
    __shared__ __align__(16) f16 Plds[2][16384];
    __shared__ __align__(16) f16 Qlds[2][16384];

    const int tid  = threadIdx.x;
    const int lane = tid & 63;
    const int wid  = tid >> 6;
    const int wm   = wid >> 2;          // 0..1
    const int wn   = wid & 3;           // 0..3

    const int wg  = blockIdx.x;
    const int swz = (wg & 7) * 32 + (wg >> 3);
    const int b   = swz >> 2;
    const int tt  = swz & 3;
    const int m0  = (tt >> 1) * 256;
    const int n0  = (tt & 1) * 256;

    const f16* Pb = P + (size_t)b * pstr;
    const f16* Qb = Qt + (size_t)b * qstr;

    const int srow = tid >> 3;                   // 0..63
    const int sswz = (tid & 7) ^ (srow & 7);

    const int fr  = lane & 15;
    const int fs  = lane >> 4;
    const int fx  = fr & 7;

    auto stage = [&](const f16* __restrict__ Gb, int row0, f16* lds, int k0) {
        #pragma unroll
        for (int r = 0; r < 4; ++r) {
            const f16* src = Gb + (size_t)(row0 + r * 64 + srow) * 512 + k0 + sswz * 8;
            gload_lds16(src, lds + r * 4096 + tid * 8);
        }
    };

    f32x4 acc[8][4] = {};

    stage(Pb, m0, &Plds[0][0], 0);
    stage(Qb, n0, &Qlds[0][0], 0);
    asm volatile("s_waitcnt vmcnt(0)" ::: "memory");
    __builtin_amdgcn_sched_barrier(0);
    __builtin_amdgcn_s_barrier();

    for (int t = 0; t < 8; ++t) {
        const int nb = t & 1;
        if (t < 7) {
            stage(Pb, m0, &Plds[nb ^ 1][0], (t + 1) * 64);
            stage(Qb, n0, &Qlds[nb ^ 1][0], (t + 1) * 64);
        }
        const f16* Pl = &Plds[nb][0];
        const f16* Ql = &Qlds[nb][0];
        #pragma unroll
        for (int krep = 0; krep < 2; ++krep) {
            const int sp = ((fs + krep * 4) ^ fx) * 8;
            f16x8 af[8], bf[4];
            #pragma unroll
            for (int mi = 0; mi < 8; ++mi)
                af[mi] = *(const f16x8*)&Pl[(wm * 128 + mi * 16 + fr) * 64 + sp];
            #pragma unroll
            for (int ni = 0; ni < 4; ++ni)
                bf[ni] = *(const f16x8*)&Ql[(wn * 64 + ni * 16 + fr) * 64 + sp];
            __builtin_amdgcn_s_setprio(1);
            #pragma unroll
            for (int mi = 0; mi < 8; ++mi)
                #pragma unroll
                for (int ni = 0; ni < 4; ++ni)
                    acc[mi][ni] = __builtin_amdgcn_mfma_f32_16x16x32_f16(
                        af[mi], bf[ni], acc[mi][ni], 0, 0, 0);
            __builtin_amdgcn_s_setprio(0);
        }
        asm volatile("s_waitcnt vmcnt(0) lgkmcnt(0)" ::: "memory");
        __builtin_amdgcn_sched_barrier(0);
        __builtin_amdgcn_s_barrier();
    }

    const int cmb = (lane >> 4) * 4;
    #pragma unroll
    for (int mi = 0; mi < 8; ++mi) {
        #pragma unroll
        for (int ni = 0; ni < 4; ++ni) {
            const int n = n0 + wn * 64 + ni * 16 + fr;
            const int m = m0 + wm * 128 + mi * 16 + cmb;
            float v[4];
            #pragma unroll
            for (int q = 0; q < 4; ++q) {
                float x = acc[mi][ni][q] * iscale;
                if (BIAS) x += bias[m + q];
                if (RELU) x = fmaxf(x, 0.f);
                v[q] = x * oscale;
            }
            if (OUTF32) {
                float* Cb = (float*)Cout + (size_t)b * cstr;
                f32x4 o; o[0] = v[0]; o[1] = v[1]; o[2] = v[2]; o[3] = v[3];
                *(f32x4*)&Cb[(size_t)n * 512 + m] = o;
            } else {
                f16* Cb = (f16*)Cout + (size_t)b * cstr;
                f16x4 o; o[0] = (f16)v[0]; o[1] = (f16)v[1]; o[2] = (f16)v[2]; o[3] = (f16)v[3];
                *(f16x4*)&Cb[(size_t)n * 512 + m] = o;
            }
        }
    }
}

extern "C" void kernel_launch(void* const* d_in, const int* in_sizes, int n_in,
                              void* d_out, int out_size, void* d_ws, size_t ws_size,
                              hipStream_t stream) {
    const float* X0  = (const float*)d_in[0];
    const float* adj = (const float*)d_in[1];
    const float* W1  = (const float*)d_in[2];
    const float* b1  = (const float*)d_in[3];
    const float* W2  = (const float*)d_in[4];
    const float* b2  = (const float*)d_in[5];
    const float* W3  = (const float*)d_in[6];
    const float* b3  = (const float*)d_in[7];

    uint8_t* ws = (uint8_t*)d_ws;
    float* rbuf = (float*)ws;                              // 128 KiB
    f16* Wt1 = (f16*)(ws + 131072);                        // 3 x 512 KiB
    f16* Wt2 = Wt1 + NN;
    f16* Wt3 = Wt2 + NN;
    f16* A_h = (f16*)(ws + 131072 + (size_t)3 * NN * 2);   // 32 MiB
    f16* Xa  = A_h + (size_t)NB * NN;                      // 32 MiB (activations)
    f16* S_t = Xa + (size_t)NB * NN;                       // 32 MiB
    float* part = (float*)S_t;   // 2 MiB, aliased: S_t first written by G1 (after fin)

    k_aux1 <<<dim3(1216),     dim3(256), 0, stream>>>(adj, part, W1, W2, W3, Wt1);
    k_fin  <<<dim3(128),      dim3(256), 0, stream>>>(part, rbuf);
    k_makeA<<<dim3(8, 8, NB), dim3(256), 0, stream>>>(adj, rbuf, A_h);

    // scales: X0 x1; W stored x64; A stored x16; layer2/3 activations stored x256.
    gemm_cvt<<<dim3(1024), dim3(256), 0, stream>>>(X0, Wt1, S_t, 1.f / 64.f);

    dim3 gg(256), gb(512);
    gemm_tn_ct<true,  true,  false><<<gg, gb, 0, stream>>>(S_t, (size_t)NN, A_h, (size_t)NN, Xa, (size_t)NN, b1, 1.f / 16.f, 1.f);
    gemm_tn_ct<false, false, false><<<gg, gb, 0, stream>>>(Xa, (size_t)NN, Wt2, (size_t)0,  S_t, (size_t)NN, nullptr, 1.f, 4.f);
    gemm_tn_ct<true,  true,  false><<<gg, gb, 0, stream>>>(S_t, (size_t)NN, A_h, (size_t)NN, Xa, (size_t)NN, b2, 1.f / 4096.f, 256.f);
    gemm_tn_ct<false, false, false><<<gg, gb, 0, stream>>>(Xa, (size_t)NN, Wt3, (size_t)0,  S_t, (size_t)NN, nullptr, 1.f, 1.f / 64.f);
    gemm_tn_ct<true,  false, true ><<<gg, gb, 0, stream>>>(S_t, (size_t)NN, A_h, (size_t)NN, d_out, (size_t)NN, b3, 1.f / 4096.f, 1.f);
}